// Round 12
// baseline (297.783 us; speedup 1.0000x reference)
//
#include <hip/hip_runtime.h>
#include <math.h>

#define NGRAPH 64
#define NPER   256
#define NNODE  (NGRAPH*NPER)      // 16384
#define CDIM   64
#define NELEM  10
#define NEDGE  (NNODE*24)         // 393216
#define RMAX2  25.0f
#define CE     160                // edges per staged chunk (k_am) -- R7 measured optimum

typedef _Float16 half8 __attribute__((ext_vector_type(8)));
typedef float floatx4 __attribute__((ext_vector_type(4)));

__device__ __forceinline__ float silu_f(float x){ return x/(1.f+__expf(-x)); }

// ---------------------------------------------------------------- mega init:
// blocks [0,4096): embedding + zidx + out_q zero (4 nodes/block)
// blocks [4096,4160): per-graph prep (E0 sums, zero deg/cursor/ctr/te/dip)
// blocks [4160,4162): weight conversion to f16 frag-linear
__global__ __launch_bounds__(256) void k_init0(
    const float* __restrict__ attrs, const float* __restrict__ E0,
    const float* __restrict__ W_embed,
    const float* __restrict__ rW1, const float* __restrict__ rW2,
    const float* __restrict__ rW3, const float* __restrict__ rW4,
    const float* __restrict__ Wmix,
    int* __restrict__ zidx, _Float16* __restrict__ sH,
    _Float16* __restrict__ wH, _Float16* __restrict__ wmixH,
    int* __restrict__ deg, int* __restrict__ cursor,
    float* __restrict__ out_ne, float* __restrict__ out_ctr, float* __restrict__ out_q,
    float* __restrict__ out_te, float* __restrict__ out_dip)
{
  int b = blockIdx.x;
  int tid = threadIdx.x;
  if (b < 4096){
    int nl = tid>>6, ln = tid&63;
    int n = b*4 + nl;
    int z = 0;
    #pragma unroll
    for (int k = 1; k < NELEM; k++) if (attrs[n*NELEM+k] > 0.5f) z = k;
    sH[(size_t)n*64+ln] = (_Float16)W_embed[z*CDIM+ln];
    if (ln == 0){ zidx[n] = z; out_q[n] = 0.f; }
  } else if (b < 4160){
    __shared__ float red[4];
    int g = b - 4096, n = g*256 + tid;
    int z = 0;
    #pragma unroll
    for (int k = 1; k < NELEM; k++) if (attrs[n*NELEM+k] > 0.5f) z = k;
    float ev = E0[z];
    out_ne[n] = ev;
    deg[n] = 0;
    cursor[n] = 0;
    float v = ev;
    #pragma unroll
    for (int o = 32; o > 0; o >>= 1) v += __shfl_down(v, o, 64);
    if ((tid&63) == 0) red[tid>>6] = v;
    __syncthreads();
    if (tid == 0) out_ctr[g*3] = red[0]+red[1]+red[2]+red[3];
    if (tid == 1) out_ctr[g*3+1] = 0.f;
    if (tid == 2) out_ctr[g*3+2] = 0.f;
    if (tid == 3) out_te[g] = 0.f;
    if (tid >= 4 && tid < 7) out_dip[g*3 + tid - 4] = 0.f;
  } else {
    int t = b - 4160;
    int w = tid>>6, ln = tid&63, ln15 = ln&15, quad = ln>>4;
    const float* Ws[4] = {rW1 + t*512, rW2 + t*4096, rW3 + t*4096, rW4 + t*4096};
    _Float16* wHt    = wH    + (size_t)t*28*512;
    _Float16* wmixHt = wmixH + (size_t)t*24*512;
    for (int f = w; f < 28; f += 4){
      int l, kt, nt;
      if (f < 4){ l = 0; kt = 0; nt = f; }
      else { int g2 = f-4; l = 1 + g2/8; int r8 = g2&7; nt = r8>>1; kt = r8&1; }
      const float* Wp = Ws[l];
      half8 v;
      #pragma unroll
      for (int j = 0; j < 8; j++){
        int k = kt*32 + quad*8 + j;
        int c = nt*16 + ln15;
        float x = (l == 0) ? ((k < 8) ? Wp[k*64+c] : 0.f) : Wp[k*64+c];
        v[j] = (_Float16)x;
      }
      *(half8*)&wHt[((size_t)f*64 + ln)*8] = v;
    }
    const float* Wm = Wmix + (size_t)t*3*4096;
    for (int f = w; f < 24; f += 4){
      int l = f>>3, kt = (f>>2)&1, nt = f&3;
      const float* p = Wm + (size_t)l*4096 + (nt*16+ln15)*64 + kt*32 + quad*8;
      half8 v;
      #pragma unroll
      for (int j = 0; j < 8; j++) v[j] = (_Float16)p[j];
      *(half8*)&wmixHt[((size_t)f*64 + ln)*8] = v;
    }
  }
}

// ---------------------------------------------------------------- CSR: count
__global__ __launch_bounds__(256) void k_count(
    const int* __restrict__ ei, const float* __restrict__ pos, int* __restrict__ deg)
{
  int e = blockIdx.x*256 + threadIdx.x;
  int s = ei[e], d = ei[NEDGE+e];
  float vx = pos[d*3]-pos[s*3], vy = pos[d*3+1]-pos[s*3+1], vz = pos[d*3+2]-pos[s*3+2];
  if (vx*vx+vy*vy+vz*vz < RMAX2) atomicAdd(&deg[d], 1);
}

__global__ __launch_bounds__(1024) void k_scan(const int* __restrict__ deg, int* __restrict__ offs)
{
  __shared__ int sums[1024];
  int t = threadIdx.x;
  int loc[16];
  int s = 0, base = t*16;
  #pragma unroll
  for (int i = 0; i < 16; i++){ loc[i] = s; s += deg[base+i]; }
  sums[t] = s;
  __syncthreads();
  for (int off = 1; off < 1024; off <<= 1){
    int v = (t >= off) ? sums[t-off] : 0;
    __syncthreads();
    sums[t] += v;
    __syncthreads();
  }
  int pre = (t > 0) ? sums[t-1] : 0;
  #pragma unroll
  for (int i = 0; i < 16; i++) offs[base+i] = pre + loc[i];
  if (t == 1023) offs[NNODE] = pre + s;
}

// ---------------------------------------------------------------- CSR: fill + geometry (f16, CSR-slot order)
__global__ __launch_bounds__(256) void k_fill(
    const int* __restrict__ ei, const float* __restrict__ pos,
    const int* __restrict__ offs, int* __restrict__ cursor,
    int* __restrict__ srcC, _Float16* __restrict__ efH, _Float16* __restrict__ shH)
{
  int e = blockIdx.x*256 + threadIdx.x;
  int s = ei[e], d = ei[NEDGE+e];
  float vx = pos[d*3]-pos[s*3], vy = pos[d*3+1]-pos[s*3+1], vz = pos[d*3+2]-pos[s*3+2];
  float r2 = vx*vx+vy*vy+vz*vz;
  if (r2 >= RMAX2) return;
  int p = atomicAdd(&cursor[d], 1);
  int slot = offs[d] + p;
  srcC[slot] = s;
  float r = sqrtf(r2);
  float inv = 1.f/fmaxf(r, 1e-9f);
  float x_ = vx*inv, y_ = vy*inv, z_ = vz*inv;
  const float s3 = 1.7320508075688772f, s15 = 3.872983346207417f, s5 = 2.2360679774997896f;
  half8 sv0, sv1;
  sv0[0] = (_Float16)1.f;
  sv0[1] = (_Float16)(s3*x_); sv0[2] = (_Float16)(s3*y_); sv0[3] = (_Float16)(s3*z_);
  sv0[4] = (_Float16)(s15*x_*y_); sv0[5] = (_Float16)(s15*y_*z_);
  sv0[6] = (_Float16)(0.5f*s5*(3.f*z_*z_-1.f)); sv0[7] = (_Float16)(s15*x_*z_);
  #pragma unroll
  for (int j = 0; j < 8; j++) sv1[j] = (_Float16)0.f;
  sv1[0] = (_Float16)(0.5f*s15*(x_*x_-y_*y_));
  *(half8*)&shH[(size_t)slot*16]     = sv0;
  *(half8*)&shH[(size_t)slot*16 + 8] = sv1;
  float xx = r*0.2f;
  float x2 = xx*xx;
  float x5 = x2*x2*xx;
  float env = 1.f - 21.f*x5 + 35.f*x5*xx - 15.f*x5*x2;
  float pref = 0.6324555320336759f*inv*env;
  const float PI_ = 3.14159265358979323846f;
  // sin(n*pi*x) via Chebyshev recurrence: 1 sincos + 7 FMAs
  float s1, c1;
  __sincosf(PI_*xx, &s1, &c1);
  float twoC = 2.f*c1;
  float sm1 = 0.f, scc = s1;
  half8 ev, z8;
  #pragma unroll
  for (int b = 0; b < 8; b++){
    ev[b] = (_Float16)(pref*scc);
    float nxt = twoC*scc - sm1;
    sm1 = scc; scc = nxt;
  }
  #pragma unroll
  for (int j = 0; j < 8; j++) z8[j] = (_Float16)0.f;
  _Float16* efp = efH + (size_t)slot*32;
  *(half8*)&efp[0]  = ev;
  *(half8*)&efp[8]  = z8;
  *(half8*)&efp[16] = z8;
  *(half8*)&efp[24] = z8;
}

// ---------------------------------------------------------------- radial MLP via f16 MFMA -> RC(f16) = R*s_src
__global__ __launch_bounds__(256) void k_R(
    const _Float16* __restrict__ efH, const int* __restrict__ srcC,
    const _Float16* __restrict__ sH, const int* __restrict__ nact_p,
    const _Float16* __restrict__ wHt, _Float16* __restrict__ RCh)
{
  __shared__ __align__(16) _Float16 hS[64*72];
  __shared__ int srcS[64];
  int nact = *nact_p;
  int ebase = blockIdx.x*64;
  if (ebase >= nact) return;
  int tid = threadIdx.x;
  int w = tid>>6, ln = tid&63, ln15 = ln&15, quad = ln>>4;

  half8 bL1 = *(const half8*)&wHt[((size_t)(0 + w)*64 + ln)*8];
  half8 bf[3][2];
  #pragma unroll
  for (int l = 0; l < 3; l++){
    bf[l][0] = *(const half8*)&wHt[((size_t)(4 + l*8 + w*2 + 0)*64 + ln)*8];
    bf[l][1] = *(const half8*)&wHt[((size_t)(4 + l*8 + w*2 + 1)*64 + ln)*8];
  }
  if (tid < 64){
    int idx = ebase + tid; if (idx > nact-1) idx = nact-1;
    srcS[tid] = srcC[idx];
  }

  floatx4 zero = {0.f, 0.f, 0.f, 0.f};
  floatx4 acc[4];

  // layer 1: A direct from global (K=8 padded to 32)
  #pragma unroll
  for (int mt = 0; mt < 4; mt++){
    int idx = ebase + mt*16 + ln15; if (idx > nact-1) idx = nact-1;
    half8 a = *(const half8*)&efH[(size_t)idx*32 + quad*8];
    acc[mt] = __builtin_amdgcn_mfma_f32_16x16x32_f16(a, bL1, zero, 0, 0, 0);
  }
  #pragma unroll
  for (int mt = 0; mt < 4; mt++)
    #pragma unroll
    for (int r = 0; r < 4; r++)
      hS[(mt*16 + quad*4 + r)*72 + w*16 + ln15] = (_Float16)silu_f(acc[mt][r]);
  __syncthreads();

  // prefetch s_src (consumed at the very end)
  float sv[16];
  #pragma unroll
  for (int mt = 0; mt < 4; mt++)
    #pragma unroll
    for (int r = 0; r < 4; r++){
      int el = mt*16 + quad*4 + r;
      sv[mt*4+r] = (float)sH[(size_t)srcS[el]*64 + w*16 + ln15];
    }

  // layers 2..4
  #pragma unroll
  for (int l = 0; l < 3; l++){
    #pragma unroll
    for (int mt = 0; mt < 4; mt++){
      half8 a0 = *(const half8*)&hS[(mt*16 + ln15)*72 + quad*8];
      half8 a1 = *(const half8*)&hS[(mt*16 + ln15)*72 + 32 + quad*8];
      floatx4 t0 = __builtin_amdgcn_mfma_f32_16x16x32_f16(a0, bf[l][0], zero, 0, 0, 0);
      acc[mt] = __builtin_amdgcn_mfma_f32_16x16x32_f16(a1, bf[l][1], t0, 0, 0, 0);
    }
    __syncthreads();
    if (l < 2){
      #pragma unroll
      for (int mt = 0; mt < 4; mt++)
        #pragma unroll
        for (int r = 0; r < 4; r++)
          hS[(mt*16 + quad*4 + r)*72 + w*16 + ln15] = (_Float16)silu_f(acc[mt][r]);
      __syncthreads();
    }
  }

  #pragma unroll
  for (int mt = 0; mt < 4; mt++)
    #pragma unroll
    for (int r = 0; r < 4; r++){
      int el = mt*16 + quad*4 + r;
      int idx = ebase + el; if (idx > nact-1) idx = nact-1;
      RCh[(size_t)idx*64 + w*16 + ln15] = (_Float16)(acc[mt][r] * sv[mt*4+r]);
    }
}

// ---------------------------------------------------------------- fused segment-sum + mix + product + epilogue
// Block = 16 contiguous nodes. Chunked LDS staging, register-prefetch pipelined:
// next chunk's global loads are issued before aggregating the current chunk.
__global__ __launch_bounds__(256) void k_am(
    const _Float16* __restrict__ RCh, const _Float16* __restrict__ shH,
    const int* __restrict__ offs, const _Float16* __restrict__ sH,
    _Float16* __restrict__ feats1, const _Float16* __restrict__ wmixHt,
    const int* __restrict__ zidx,
    const float* __restrict__ Wsc_t, const float* __restrict__ w2_t,
    const float* __restrict__ w3_t, const float* __restrict__ Wq_t,
    const float* __restrict__ Wr0, const float* __restrict__ Wh, const float* __restrict__ Wo,
    float* __restrict__ out_ne, float* __restrict__ out_ctr, float* __restrict__ out_q, int t)
{
  // union: stage (CE*64 + CE*16 halves = 25600B) vs aggS (9*16*72 = 20736B)
  __shared__ __align__(16) _Float16 uni[CE*80];
  __shared__ _Float16 tabS[1920];                   // f16 [Wsc|w2|w3][z][d]
  __shared__ _Float16 WhS[1024];
  __shared__ _Float16 f0S[16*64];
  __shared__ float qS[4][16], neS[4][16];
  __shared__ float WqS[64], Wr0S[64], WoS[16];
  __shared__ int zS[16];
  _Float16* stR = uni;            // [CE][64]
  _Float16* stS = uni + CE*64;    // [CE][16]
  _Float16* aggS = uni;           // [m][node][72], after stage is dead

  int blk = blockIdx.x;
  int tid = threadIdx.x;
  int w = tid>>6, ln = tid&63, ln15 = ln&15, quad = ln>>4;

  for (int i = tid; i < 1920; i += 256){
    int t3 = i/640, rem = i - t3*640;
    const float* src = (t3 == 0) ? Wsc_t : (t3 == 1) ? w2_t : w3_t;
    tabS[i] = (_Float16)src[rem];
  }
  for (int i = tid; i < 1024; i += 256) WhS[i] = (_Float16)Wh[i];
  if (tid < 64){ WqS[tid] = Wq_t[tid]; Wr0S[tid] = Wr0[tid]; }
  if (tid < 16){ WoS[tid] = Wo[tid]; zS[tid] = zidx[blk*16+tid]; }

  int beg = offs[blk*16], end = offs[blk*16+16];
  int nb[4], ne_[4];
  #pragma unroll
  for (int i = 0; i < 4; i++){
    nb[i]  = offs[blk*16 + w*4 + i];
    ne_[i] = offs[blk*16 + w*4 + i + 1];
  }

  float accn[4][9];
  #pragma unroll
  for (int i = 0; i < 4; i++)
    #pragma unroll
    for (int m = 0; m < 9; m++) accn[i][m] = 0.f;

  // register prefetch buffers (CE=160: stR needs 5 half8/thread, stS needs 2 w/ bounds)
  half8 rR[5], rS[2];
  {
    int ce0 = end - beg; if (ce0 > CE) ce0 = CE;
    #pragma unroll
    for (int k = 0; k < 5; k++){
      int i = tid + k*256;
      if (i < ce0*8) rR[k] = *(const half8*)&RCh[(size_t)beg*64 + i*8];
    }
    #pragma unroll
    for (int k = 0; k < 2; k++){
      int i = tid + k*256;
      if (i < ce0*2) rS[k] = *(const half8*)&shH[(size_t)beg*16 + i*8];
    }
  }

  for (int c0 = beg; c0 < end; c0 += CE){
    int ce = end - c0; if (ce > CE) ce = CE;
    __syncthreads();                       // stage buffer free (prev chunk consumed / tab init)
    #pragma unroll
    for (int k = 0; k < 5; k++){
      int i = tid + k*256;
      if (i < ce*8) *(half8*)&stR[i*8] = rR[k];
    }
    #pragma unroll
    for (int k = 0; k < 2; k++){
      int i = tid + k*256;
      if (i < ce*2) *(half8*)&stS[i*8] = rS[k];
    }
    __syncthreads();
    // issue next chunk's loads now; aggregation below hides their latency
    int c1 = c0 + CE;
    if (c1 < end){
      int ce1 = end - c1; if (ce1 > CE) ce1 = CE;
      #pragma unroll
      for (int k = 0; k < 5; k++){
        int i = tid + k*256;
        if (i < ce1*8) rR[k] = *(const half8*)&RCh[(size_t)c1*64 + i*8];
      }
      #pragma unroll
      for (int k = 0; k < 2; k++){
        int i = tid + k*256;
        if (i < ce1*2) rS[k] = *(const half8*)&shH[(size_t)c1*16 + i*8];
      }
    }
    #pragma unroll
    for (int i = 0; i < 4; i++){
      int pb = nb[i] > c0 ? nb[i] : c0;
      int pe = ne_[i] < c0+ce ? ne_[i] : c0+ce;
      for (int p = pb - c0; p < pe - c0; ++p){
        float rc = (float)stR[p*64 + ln];
        const _Float16* sp = &stS[p*16];
        half8 s0 = *(const half8*)sp;
        float s8 = (float)sp[8];
        accn[i][0] += rc*(float)s0[0]; accn[i][1] += rc*(float)s0[1];
        accn[i][2] += rc*(float)s0[2]; accn[i][3] += rc*(float)s0[3];
        accn[i][4] += rc*(float)s0[4]; accn[i][5] += rc*(float)s0[5];
        accn[i][6] += rc*(float)s0[6]; accn[i][7] += rc*(float)s0[7];
        accn[i][8] += rc*s8;
      }
    }
  }
  __syncthreads();                         // all consumption done; stage -> aggS
  #pragma unroll
  for (int i = 0; i < 4; i++){
    int nl = w*4 + i;
    #pragma unroll
    for (int m = 0; m < 9; m++)
      aggS[(m*16 + nl)*72 + ln] = (_Float16)(accn[i][m]*(1.f/24.f));
  }
  __syncthreads();

  // ---- mix phase: 9 planes, A from aggS, B from global f16 frags
  floatx4 zero = {0.f, 0.f, 0.f, 0.f};
  floatx4 macc[9];
  #pragma unroll
  for (int m = 0; m < 9; m++){
    int l = (m == 0) ? 0 : ((m < 4) ? 1 : 2);
    half8 a0 = *(const half8*)&aggS[(m*16 + ln15)*72 + quad*8];
    half8 a1 = *(const half8*)&aggS[(m*16 + ln15)*72 + 32 + quad*8];
    half8 b0 = *(const half8*)&wmixHt[((size_t)(l*8 + w)*64 + ln)*8];
    half8 b1 = *(const half8*)&wmixHt[((size_t)(l*8 + 4 + w)*64 + ln)*8];
    floatx4 t0 = __builtin_amdgcn_mfma_f32_16x16x32_f16(a0, b0, zero, 0, 0, 0);
    macc[m] = __builtin_amdgcn_mfma_f32_16x16x32_f16(a1, b1, t0, 0, 0, 0);
  }

  // ---- lane-local epilogue
  int d = w*16 + ln15;
  #pragma unroll
  for (int r = 0; r < 4; r++){
    int nl = quad*4 + r;
    size_t nglob = (size_t)blk*16 + nl;
    int z = zS[nl];
    float wsc = (float)tabS[z*64+d];
    float g2  = (float)tabS[640 + z*64+d];
    float g3  = (float)tabS[1280 + z*64+d];
    float s0 = macc[0][r];
    float factor = 1.f + g2*s0 + g3*s0*s0;
    float f0 = 0.f;
    #pragma unroll
    for (int m = 0; m < 9; m++){
      float fold;
      if (t == 0) fold = (m == 0) ? (float)sH[nglob*64 + d] : 0.f;
      else        fold = (float)feats1[((size_t)m*NNODE + nglob)*64 + d];
      float fnew = macc[m][r]*factor + fold*wsc;
      if (t == 0) feats1[((size_t)m*NNODE + nglob)*64 + d] = (_Float16)fnew;
      if (m == 0) f0 = fnew;
    }
    if (t == 1) f0S[nl*64 + d] = (_Float16)f0;
    float qv = f0*WqS[d];
    float nev = (t == 0) ? f0*Wr0S[d] : 0.f;
    #pragma unroll
    for (int o = 1; o < 16; o <<= 1){
      qv  += __shfl_xor(qv, o, 16);
      nev += __shfl_xor(nev, o, 16);
    }
    if (ln15 == 0){ qS[w][nl] = qv; neS[w][nl] = nev; }
  }
  __syncthreads();

  if (w == 0 && ln < 16){
    float q = qS[0][ln]+qS[1][ln]+qS[2][ln]+qS[3][ln];
    out_q[blk*16+ln] += q;
    if (t == 0){
      float ne = neS[0][ln]+neS[1][ln]+neS[2][ln]+neS[3][ln];
      out_ne[blk*16+ln] += ne;
      neS[0][ln] = ne;
    }
  }
  if (t == 1 && w == 1){
    int iloc = ln>>4, j = ln&15;
    #pragma unroll
    for (int it = 0; it < 4; it++){
      int i = it*4 + iloc;
      float h = 0.f;
      #pragma unroll 8
      for (int dd = 0; dd < 64; dd++) h += (float)f0S[i*64+dd]*(float)WhS[dd*16+j];
      h = silu_f(h)*WoS[j];
      #pragma unroll
      for (int o = 1; o < 16; o <<= 1) h += __shfl_xor(h, o, 16);
      if (j == 0){ neS[0][i] = h; out_ne[blk*16+i] += h; }
    }
  }
  __syncthreads();
  if (tid == 0){
    float s = 0.f;
    #pragma unroll
    for (int i = 0; i < 16; i++) s += neS[0][i];
    atomicAdd(&out_ctr[(blk>>4)*3 + 1 + t], s);
  }
}

// ---------------------------------------------------------------- Coulomb + dipole: 4 j-chunks/graph,
// broadcast LDS reads (uniform j across block -> zero bank conflicts), row = tid.
__global__ __launch_bounds__(256) void k_coul(
    const float* __restrict__ q, const float* __restrict__ pos,
    const float* __restrict__ ctr, float* __restrict__ te, float* __restrict__ dip)
{
  __shared__ float qs[256], px[256], py[256], pz[256];
  __shared__ float red[4], redd[12];
  int g = blockIdx.x >> 2, ch = blockIdx.x & 3;
  int tid = threadIdx.x;
  int base = g*256;
  qs[tid] = q[base+tid];
  px[tid] = pos[(base+tid)*3];
  py[tid] = pos[(base+tid)*3+1];
  pz[tid] = pos[(base+tid)*3+2];
  __syncthreads();
  float qi = qs[tid], xi = px[tid], yi = py[tid], zi = pz[tid];
  float srow = 0.f;
  int j0 = ch*64;
  #pragma unroll 4
  for (int u = 0; u < 64; u++){
    int j = j0 + u;                      // block-uniform -> LDS broadcast
    float dx = xi-px[j], dy = yi-py[j], dz = zi-pz[j];
    float r = sqrtf(dx*dx+dy*dy+dz*dz + 1e-12f);
    float v = erff(0.5f*r)/r;
    srow += (j == tid) ? 0.f : qs[j]*v;
  }
  int wv = tid>>6, ln = tid&63;
  float ev = 0.5f*qi*srow;
  #pragma unroll
  for (int o = 32; o > 0; o >>= 1) ev += __shfl_down(ev, o, 64);
  if (ln == 0) red[wv] = ev;
  if (ch == 0){
    float vx = qi*xi, vy = qi*yi, vz = qi*zi;
    #pragma unroll
    for (int o = 32; o > 0; o >>= 1){
      vx += __shfl_down(vx, o, 64);
      vy += __shfl_down(vy, o, 64);
      vz += __shfl_down(vz, o, 64);
    }
    if (ln == 0){ redd[wv*3] = vx; redd[wv*3+1] = vy; redd[wv*3+2] = vz; }
  }
  __syncthreads();
  if (tid == 0){
    float e = red[0]+red[1]+red[2]+red[3];
    if (ch == 0) e += ctr[g*3] + ctr[g*3+1] + ctr[g*3+2];
    atomicAdd(&te[g], e);
  }
  if (ch == 0 && tid < 3)
    dip[g*3+tid] = redd[tid] + redd[3+tid] + redd[6+tid] + redd[9+tid];
}

// ---------------------------------------------------------------- launch
extern "C" void kernel_launch(void* const* d_in, const int* in_sizes, int n_in,
                              void* d_out, int out_size, void* d_ws, size_t ws_size,
                              hipStream_t stream)
{
  (void)in_sizes; (void)n_in; (void)out_size; (void)ws_size;
  const float* attrs   = (const float*)d_in[0];
  const float* pos     = (const float*)d_in[1];
  const int*   ei      = (const int*)d_in[2];
  const float* W_embed = (const float*)d_in[4];
  const float* E0      = (const float*)d_in[5];
  const float* rW1     = (const float*)d_in[6];
  const float* rW2     = (const float*)d_in[7];
  const float* rW3     = (const float*)d_in[8];
  const float* rW4     = (const float*)d_in[9];
  const float* Wmix    = (const float*)d_in[10];
  const float* Wsc     = (const float*)d_in[11];
  const float* w2      = (const float*)d_in[12];
  const float* w3      = (const float*)d_in[13];
  const float* Wr0     = (const float*)d_in[14];
  const float* Wh      = (const float*)d_in[15];
  const float* Wo      = (const float*)d_in[16];
  const float* Wq      = (const float*)d_in[17];

  char* base = (char*)d_ws;
  _Float16* efH   = (_Float16*)base; base += (size_t)NEDGE*32*2;
  _Float16* shH   = (_Float16*)base; base += (size_t)NEDGE*16*2 + 4096;  // slack for chunk-aligned staging reads
  _Float16* RCh   = (_Float16*)base; base += (size_t)NEDGE*64*2 + 8192;  // slack for prefetch over-read
  _Float16* sH    = (_Float16*)base; base += (size_t)NNODE*64*2;
  _Float16* feats1= (_Float16*)base; base += (size_t)9*NNODE*64*2;
  _Float16* wH    = (_Float16*)base; base += (size_t)2*28*512*2;
  _Float16* wmixH = (_Float16*)base; base += (size_t)2*24*512*2;
  int*      deg   = (int*)base;      base += (size_t)NNODE*4;
  int*      offs  = (int*)base;      base += (size_t)(NNODE+1)*4;
  int*      cursor= (int*)base;      base += (size_t)NNODE*4;
  int*      srcC  = (int*)base;      base += (size_t)NEDGE*4;
  int*      zidx  = (int*)base;      base += (size_t)NNODE*4;

  float* out_te  = (float*)d_out;
  float* out_ne  = out_te  + NGRAPH;
  float* out_ctr = out_ne  + NNODE;
  float* out_q   = out_ctr + NGRAPH*3;
  float* out_dip = out_q   + NNODE;

  k_init0<<<4162, 256, 0, stream>>>(attrs, E0, W_embed, rW1, rW2, rW3, rW4, Wmix,
      zidx, sH, wH, wmixH, deg, cursor, out_ne, out_ctr, out_q, out_te, out_dip);
  k_count<<<NEDGE/256, 256, 0, stream>>>(ei, pos, deg);
  k_scan <<<1, 1024, 0, stream>>>(deg, offs);
  k_fill <<<NEDGE/256, 256, 0, stream>>>(ei, pos, offs, cursor, srcC, efH, shH);

  for (int t = 0; t < 2; t++){
    const _Float16* sprev = t ? feats1 : sH;   // plane 0 of feats1 == next-iter node scalars
    k_R <<<NEDGE/64, 256, 0, stream>>>(efH, srcC, sprev, offs+NNODE,
        wH + (size_t)t*28*512, RCh);
    k_am<<<NNODE/16, 256, 0, stream>>>(RCh, shH, offs, sH, feats1,
        wmixH + (size_t)t*24*512, zidx,
        Wsc + t*NELEM*CDIM, w2 + t*NELEM*CDIM, w3 + t*NELEM*CDIM, Wq + t*CDIM,
        Wr0, Wh, Wo, out_ne, out_ctr, out_q, t);
  }
  k_coul<<<NGRAPH*4, 256, 0, stream>>>(out_q, pos, out_ctr, out_te, out_dip);
}

// Round 13
// 260.974 us; speedup vs baseline: 1.1410x; 1.1410x over previous
//
#include <hip/hip_runtime.h>
#include <math.h>

#define NGRAPH 64
#define NPER   256
#define NNODE  (NGRAPH*NPER)      // 16384
#define CDIM   64
#define NELEM  10
#define NEDGE  (NNODE*24)         // 393216
#define RMAX2  25.0f
#define CE     192                // edges per staged chunk: covers ~all 16-node blocks in ONE chunk

typedef _Float16 half8 __attribute__((ext_vector_type(8)));
typedef float floatx4 __attribute__((ext_vector_type(4)));

__device__ __forceinline__ float silu_f(float x){ return x/(1.f+__expf(-x)); }

// ---------------------------------------------------------------- mega init:
// blocks [0,4096): embedding + zidx + out_q zero (4 nodes/block)
// blocks [4096,4160): per-graph prep (E0 sums, zero deg/cursor/ctr/te/dip)
// blocks [4160,4162): weight conversion to f16 frag-linear
__global__ __launch_bounds__(256) void k_init0(
    const float* __restrict__ attrs, const float* __restrict__ E0,
    const float* __restrict__ W_embed,
    const float* __restrict__ rW1, const float* __restrict__ rW2,
    const float* __restrict__ rW3, const float* __restrict__ rW4,
    const float* __restrict__ Wmix,
    int* __restrict__ zidx, _Float16* __restrict__ sH,
    _Float16* __restrict__ wH, _Float16* __restrict__ wmixH,
    int* __restrict__ deg, int* __restrict__ cursor,
    float* __restrict__ out_ne, float* __restrict__ out_ctr, float* __restrict__ out_q,
    float* __restrict__ out_te, float* __restrict__ out_dip)
{
  int b = blockIdx.x;
  int tid = threadIdx.x;
  if (b < 4096){
    int nl = tid>>6, ln = tid&63;
    int n = b*4 + nl;
    int z = 0;
    #pragma unroll
    for (int k = 1; k < NELEM; k++) if (attrs[n*NELEM+k] > 0.5f) z = k;
    sH[(size_t)n*64+ln] = (_Float16)W_embed[z*CDIM+ln];
    if (ln == 0){ zidx[n] = z; out_q[n] = 0.f; }
  } else if (b < 4160){
    __shared__ float red[4];
    int g = b - 4096, n = g*256 + tid;
    int z = 0;
    #pragma unroll
    for (int k = 1; k < NELEM; k++) if (attrs[n*NELEM+k] > 0.5f) z = k;
    float ev = E0[z];
    out_ne[n] = ev;
    deg[n] = 0;
    cursor[n] = 0;
    float v = ev;
    #pragma unroll
    for (int o = 32; o > 0; o >>= 1) v += __shfl_down(v, o, 64);
    if ((tid&63) == 0) red[tid>>6] = v;
    __syncthreads();
    if (tid == 0) out_ctr[g*3] = red[0]+red[1]+red[2]+red[3];
    if (tid == 1) out_ctr[g*3+1] = 0.f;
    if (tid == 2) out_ctr[g*3+2] = 0.f;
    if (tid == 3) out_te[g] = 0.f;
    if (tid >= 4 && tid < 7) out_dip[g*3 + tid - 4] = 0.f;
  } else {
    int t = b - 4160;
    int w = tid>>6, ln = tid&63, ln15 = ln&15, quad = ln>>4;
    const float* Ws[4] = {rW1 + t*512, rW2 + t*4096, rW3 + t*4096, rW4 + t*4096};
    _Float16* wHt    = wH    + (size_t)t*28*512;
    _Float16* wmixHt = wmixH + (size_t)t*24*512;
    for (int f = w; f < 28; f += 4){
      int l, kt, nt;
      if (f < 4){ l = 0; kt = 0; nt = f; }
      else { int g2 = f-4; l = 1 + g2/8; int r8 = g2&7; nt = r8>>1; kt = r8&1; }
      const float* Wp = Ws[l];
      half8 v;
      #pragma unroll
      for (int j = 0; j < 8; j++){
        int k = kt*32 + quad*8 + j;
        int c = nt*16 + ln15;
        float x = (l == 0) ? ((k < 8) ? Wp[k*64+c] : 0.f) : Wp[k*64+c];
        v[j] = (_Float16)x;
      }
      *(half8*)&wHt[((size_t)f*64 + ln)*8] = v;
    }
    const float* Wm = Wmix + (size_t)t*3*4096;
    for (int f = w; f < 24; f += 4){
      int l = f>>3, kt = (f>>2)&1, nt = f&3;
      const float* p = Wm + (size_t)l*4096 + (nt*16+ln15)*64 + kt*32 + quad*8;
      half8 v;
      #pragma unroll
      for (int j = 0; j < 8; j++) v[j] = (_Float16)p[j];
      *(half8*)&wmixHt[((size_t)f*64 + ln)*8] = v;
    }
  }
}

// ---------------------------------------------------------------- CSR: count
__global__ __launch_bounds__(256) void k_count(
    const int* __restrict__ ei, const float* __restrict__ pos, int* __restrict__ deg)
{
  int e = blockIdx.x*256 + threadIdx.x;
  int s = ei[e], d = ei[NEDGE+e];
  float vx = pos[d*3]-pos[s*3], vy = pos[d*3+1]-pos[s*3+1], vz = pos[d*3+2]-pos[s*3+2];
  if (vx*vx+vy*vy+vz*vz < RMAX2) atomicAdd(&deg[d], 1);
}

__global__ __launch_bounds__(1024) void k_scan(const int* __restrict__ deg, int* __restrict__ offs)
{
  __shared__ int sums[1024];
  int t = threadIdx.x;
  int loc[16];
  int s = 0, base = t*16;
  #pragma unroll
  for (int i = 0; i < 16; i++){ loc[i] = s; s += deg[base+i]; }
  sums[t] = s;
  __syncthreads();
  for (int off = 1; off < 1024; off <<= 1){
    int v = (t >= off) ? sums[t-off] : 0;
    __syncthreads();
    sums[t] += v;
    __syncthreads();
  }
  int pre = (t > 0) ? sums[t-1] : 0;
  #pragma unroll
  for (int i = 0; i < 16; i++) offs[base+i] = pre + loc[i];
  if (t == 1023) offs[NNODE] = pre + s;
}

// ---------------------------------------------------------------- CSR: fill + geometry (f16, CSR-slot order)
__global__ __launch_bounds__(256) void k_fill(
    const int* __restrict__ ei, const float* __restrict__ pos,
    const int* __restrict__ offs, int* __restrict__ cursor,
    int* __restrict__ srcC, _Float16* __restrict__ efH, _Float16* __restrict__ shH)
{
  int e = blockIdx.x*256 + threadIdx.x;
  int s = ei[e], d = ei[NEDGE+e];
  float vx = pos[d*3]-pos[s*3], vy = pos[d*3+1]-pos[s*3+1], vz = pos[d*3+2]-pos[s*3+2];
  float r2 = vx*vx+vy*vy+vz*vz;
  if (r2 >= RMAX2) return;
  int p = atomicAdd(&cursor[d], 1);
  int slot = offs[d] + p;
  srcC[slot] = s;
  float r = sqrtf(r2);
  float inv = 1.f/fmaxf(r, 1e-9f);
  float x_ = vx*inv, y_ = vy*inv, z_ = vz*inv;
  const float s3 = 1.7320508075688772f, s15 = 3.872983346207417f, s5 = 2.2360679774997896f;
  half8 sv0, sv1;
  sv0[0] = (_Float16)1.f;
  sv0[1] = (_Float16)(s3*x_); sv0[2] = (_Float16)(s3*y_); sv0[3] = (_Float16)(s3*z_);
  sv0[4] = (_Float16)(s15*x_*y_); sv0[5] = (_Float16)(s15*y_*z_);
  sv0[6] = (_Float16)(0.5f*s5*(3.f*z_*z_-1.f)); sv0[7] = (_Float16)(s15*x_*z_);
  #pragma unroll
  for (int j = 0; j < 8; j++) sv1[j] = (_Float16)0.f;
  sv1[0] = (_Float16)(0.5f*s15*(x_*x_-y_*y_));
  *(half8*)&shH[(size_t)slot*16]     = sv0;
  *(half8*)&shH[(size_t)slot*16 + 8] = sv1;
  float xx = r*0.2f;
  float x2 = xx*xx;
  float x5 = x2*x2*xx;
  float env = 1.f - 21.f*x5 + 35.f*x5*xx - 15.f*x5*x2;
  float pref = 0.6324555320336759f*inv*env;
  const float PI_ = 3.14159265358979323846f;
  // sin(n*pi*x) via Chebyshev recurrence: 1 sincos + 7 FMAs
  float s1, c1;
  __sincosf(PI_*xx, &s1, &c1);
  float twoC = 2.f*c1;
  float sm1 = 0.f, scc = s1;
  half8 ev, z8;
  #pragma unroll
  for (int b = 0; b < 8; b++){
    ev[b] = (_Float16)(pref*scc);
    float nxt = twoC*scc - sm1;
    sm1 = scc; scc = nxt;
  }
  #pragma unroll
  for (int j = 0; j < 8; j++) z8[j] = (_Float16)0.f;
  _Float16* efp = efH + (size_t)slot*32;
  *(half8*)&efp[0]  = ev;
  *(half8*)&efp[8]  = z8;
  *(half8*)&efp[16] = z8;
  *(half8*)&efp[24] = z8;
}

// ---------------------------------------------------------------- radial MLP via f16 MFMA -> RC(f16) = R*s_src
__global__ __launch_bounds__(256) void k_R(
    const _Float16* __restrict__ efH, const int* __restrict__ srcC,
    const _Float16* __restrict__ sH, const int* __restrict__ nact_p,
    const _Float16* __restrict__ wHt, _Float16* __restrict__ RCh)
{
  __shared__ __align__(16) _Float16 hS[64*72];
  __shared__ int srcS[64];
  int nact = *nact_p;
  int ebase = blockIdx.x*64;
  if (ebase >= nact) return;
  int tid = threadIdx.x;
  int w = tid>>6, ln = tid&63, ln15 = ln&15, quad = ln>>4;

  half8 bL1 = *(const half8*)&wHt[((size_t)(0 + w)*64 + ln)*8];
  half8 bf[3][2];
  #pragma unroll
  for (int l = 0; l < 3; l++){
    bf[l][0] = *(const half8*)&wHt[((size_t)(4 + l*8 + w*2 + 0)*64 + ln)*8];
    bf[l][1] = *(const half8*)&wHt[((size_t)(4 + l*8 + w*2 + 1)*64 + ln)*8];
  }
  if (tid < 64){
    int idx = ebase + tid; if (idx > nact-1) idx = nact-1;
    srcS[tid] = srcC[idx];
  }

  floatx4 zero = {0.f, 0.f, 0.f, 0.f};
  floatx4 acc[4];

  // layer 1: A direct from global (K=8 padded to 32)
  #pragma unroll
  for (int mt = 0; mt < 4; mt++){
    int idx = ebase + mt*16 + ln15; if (idx > nact-1) idx = nact-1;
    half8 a = *(const half8*)&efH[(size_t)idx*32 + quad*8];
    acc[mt] = __builtin_amdgcn_mfma_f32_16x16x32_f16(a, bL1, zero, 0, 0, 0);
  }
  #pragma unroll
  for (int mt = 0; mt < 4; mt++)
    #pragma unroll
    for (int r = 0; r < 4; r++)
      hS[(mt*16 + quad*4 + r)*72 + w*16 + ln15] = (_Float16)silu_f(acc[mt][r]);
  __syncthreads();

  // prefetch s_src (consumed at the very end)
  float sv[16];
  #pragma unroll
  for (int mt = 0; mt < 4; mt++)
    #pragma unroll
    for (int r = 0; r < 4; r++){
      int el = mt*16 + quad*4 + r;
      sv[mt*4+r] = (float)sH[(size_t)srcS[el]*64 + w*16 + ln15];
    }

  // layers 2..4
  #pragma unroll
  for (int l = 0; l < 3; l++){
    #pragma unroll
    for (int mt = 0; mt < 4; mt++){
      half8 a0 = *(const half8*)&hS[(mt*16 + ln15)*72 + quad*8];
      half8 a1 = *(const half8*)&hS[(mt*16 + ln15)*72 + 32 + quad*8];
      floatx4 t0 = __builtin_amdgcn_mfma_f32_16x16x32_f16(a0, bf[l][0], zero, 0, 0, 0);
      acc[mt] = __builtin_amdgcn_mfma_f32_16x16x32_f16(a1, bf[l][1], t0, 0, 0, 0);
    }
    __syncthreads();
    if (l < 2){
      #pragma unroll
      for (int mt = 0; mt < 4; mt++)
        #pragma unroll
        for (int r = 0; r < 4; r++)
          hS[(mt*16 + quad*4 + r)*72 + w*16 + ln15] = (_Float16)silu_f(acc[mt][r]);
      __syncthreads();
    }
  }

  #pragma unroll
  for (int mt = 0; mt < 4; mt++)
    #pragma unroll
    for (int r = 0; r < 4; r++){
      int el = mt*16 + quad*4 + r;
      int idx = ebase + el; if (idx > nact-1) idx = nact-1;
      RCh[(size_t)idx*64 + w*16 + ln15] = (_Float16)(acc[mt][r] * sv[mt*4+r]);
    }
}

// ---------------------------------------------------------------- fused segment-sum + mix + product + epilogue
// Block = 16 contiguous nodes. CE=192: ~all blocks stage their whole edge range in ONE chunk.
__global__ __launch_bounds__(256) void k_am(
    const _Float16* __restrict__ RCh, const _Float16* __restrict__ shH,
    const int* __restrict__ offs, const _Float16* __restrict__ sH,
    _Float16* __restrict__ feats1, const _Float16* __restrict__ wmixHt,
    const int* __restrict__ zidx,
    const float* __restrict__ Wsc_t, const float* __restrict__ w2_t,
    const float* __restrict__ w3_t, const float* __restrict__ Wq_t,
    const float* __restrict__ Wr0, const float* __restrict__ Wh, const float* __restrict__ Wo,
    float* __restrict__ out_ne, float* __restrict__ out_ctr, float* __restrict__ out_q, int t)
{
  // union: stage (CE*64 + CE*16 halves = 30720B) vs aggS (9*16*72 = 20736 halves... bytes: 20736*2=41472? no: 9*16*72=10368 halves = 20736B)
  __shared__ __align__(16) _Float16 uni[CE*80];
  __shared__ _Float16 tabS[1920];                   // f16 [Wsc|w2|w3][z][d]
  __shared__ _Float16 WhS[1024];
  __shared__ _Float16 f0S[16*64];
  __shared__ float qS[4][16], neS[4][16];
  __shared__ float WqS[64], Wr0S[64], WoS[16];
  __shared__ int zS[16];
  _Float16* stR = uni;            // [CE][64]
  _Float16* stS = uni + CE*64;    // [CE][16]
  _Float16* aggS = uni;           // [m][node][72], after stage is dead

  int blk = blockIdx.x;
  int tid = threadIdx.x;
  int w = tid>>6, ln = tid&63, ln15 = ln&15, quad = ln>>4;

  for (int i = tid; i < 1920; i += 256){
    int t3 = i/640, rem = i - t3*640;
    const float* src = (t3 == 0) ? Wsc_t : (t3 == 1) ? w2_t : w3_t;
    tabS[i] = (_Float16)src[rem];
  }
  for (int i = tid; i < 1024; i += 256) WhS[i] = (_Float16)Wh[i];
  if (tid < 64){ WqS[tid] = Wq_t[tid]; Wr0S[tid] = Wr0[tid]; }
  if (tid < 16){ WoS[tid] = Wo[tid]; zS[tid] = zidx[blk*16+tid]; }

  int beg = offs[blk*16], end = offs[blk*16+16];
  int nb[4], ne_[4];
  #pragma unroll
  for (int i = 0; i < 4; i++){
    nb[i]  = offs[blk*16 + w*4 + i];
    ne_[i] = offs[blk*16 + w*4 + i + 1];
  }

  float accn[4][9];
  #pragma unroll
  for (int i = 0; i < 4; i++)
    #pragma unroll
    for (int m = 0; m < 9; m++) accn[i][m] = 0.f;

  for (int c0 = beg; c0 < end; c0 += CE){
    int ce = end - c0; if (ce > CE) ce = CE;
    __syncthreads();                       // stage buffer free (covers tab loads on first iter)
    for (int i = tid; i < ce*8; i += 256)
      *(half8*)&stR[i*8] = *(const half8*)&RCh[(size_t)c0*64 + i*8];
    for (int i = tid; i < ce*2; i += 256)
      *(half8*)&stS[i*8] = *(const half8*)&shH[(size_t)c0*16 + i*8];
    __syncthreads();
    #pragma unroll
    for (int i = 0; i < 4; i++){
      int pb = nb[i] > c0 ? nb[i] : c0;
      int pe = ne_[i] < c0+ce ? ne_[i] : c0+ce;
      for (int p = pb - c0; p < pe - c0; ++p){
        float rc = (float)stR[p*64 + ln];
        const _Float16* sp = &stS[p*16];
        half8 s0 = *(const half8*)sp;
        float s8 = (float)sp[8];
        accn[i][0] += rc*(float)s0[0]; accn[i][1] += rc*(float)s0[1];
        accn[i][2] += rc*(float)s0[2]; accn[i][3] += rc*(float)s0[3];
        accn[i][4] += rc*(float)s0[4]; accn[i][5] += rc*(float)s0[5];
        accn[i][6] += rc*(float)s0[6]; accn[i][7] += rc*(float)s0[7];
        accn[i][8] += rc*s8;
      }
    }
  }
  __syncthreads();                         // all consumption done; stage -> aggS
  #pragma unroll
  for (int i = 0; i < 4; i++){
    int nl = w*4 + i;
    #pragma unroll
    for (int m = 0; m < 9; m++)
      aggS[(m*16 + nl)*72 + ln] = (_Float16)(accn[i][m]*(1.f/24.f));
  }
  __syncthreads();

  // ---- mix phase: 9 planes, A from aggS, B from global f16 frags
  floatx4 zero = {0.f, 0.f, 0.f, 0.f};
  floatx4 macc[9];
  #pragma unroll
  for (int m = 0; m < 9; m++){
    int l = (m == 0) ? 0 : ((m < 4) ? 1 : 2);
    half8 a0 = *(const half8*)&aggS[(m*16 + ln15)*72 + quad*8];
    half8 a1 = *(const half8*)&aggS[(m*16 + ln15)*72 + 32 + quad*8];
    half8 b0 = *(const half8*)&wmixHt[((size_t)(l*8 + w)*64 + ln)*8];
    half8 b1 = *(const half8*)&wmixHt[((size_t)(l*8 + 4 + w)*64 + ln)*8];
    floatx4 t0 = __builtin_amdgcn_mfma_f32_16x16x32_f16(a0, b0, zero, 0, 0, 0);
    macc[m] = __builtin_amdgcn_mfma_f32_16x16x32_f16(a1, b1, t0, 0, 0, 0);
  }

  // ---- lane-local epilogue
  int d = w*16 + ln15;
  #pragma unroll
  for (int r = 0; r < 4; r++){
    int nl = quad*4 + r;
    size_t nglob = (size_t)blk*16 + nl;
    int z = zS[nl];
    float wsc = (float)tabS[z*64+d];
    float g2  = (float)tabS[640 + z*64+d];
    float g3  = (float)tabS[1280 + z*64+d];
    float s0 = macc[0][r];
    float factor = 1.f + g2*s0 + g3*s0*s0;
    float f0 = 0.f;
    #pragma unroll
    for (int m = 0; m < 9; m++){
      float fold;
      if (t == 0) fold = (m == 0) ? (float)sH[nglob*64 + d] : 0.f;
      else        fold = (float)feats1[((size_t)m*NNODE + nglob)*64 + d];
      float fnew = macc[m][r]*factor + fold*wsc;
      if (t == 0) feats1[((size_t)m*NNODE + nglob)*64 + d] = (_Float16)fnew;
      if (m == 0) f0 = fnew;
    }
    if (t == 1) f0S[nl*64 + d] = (_Float16)f0;
    float qv = f0*WqS[d];
    float nev = (t == 0) ? f0*Wr0S[d] : 0.f;
    #pragma unroll
    for (int o = 1; o < 16; o <<= 1){
      qv  += __shfl_xor(qv, o, 16);
      nev += __shfl_xor(nev, o, 16);
    }
    if (ln15 == 0){ qS[w][nl] = qv; neS[w][nl] = nev; }
  }
  __syncthreads();

  if (w == 0 && ln < 16){
    float q = qS[0][ln]+qS[1][ln]+qS[2][ln]+qS[3][ln];
    out_q[blk*16+ln] += q;
    if (t == 0){
      float ne = neS[0][ln]+neS[1][ln]+neS[2][ln]+neS[3][ln];
      out_ne[blk*16+ln] += ne;
      neS[0][ln] = ne;
    }
  }
  if (t == 1 && w == 1){
    int iloc = ln>>4, j = ln&15;
    #pragma unroll
    for (int it = 0; it < 4; it++){
      int i = it*4 + iloc;
      float h = 0.f;
      #pragma unroll 8
      for (int dd = 0; dd < 64; dd++) h += (float)f0S[i*64+dd]*(float)WhS[dd*16+j];
      h = silu_f(h)*WoS[j];
      #pragma unroll
      for (int o = 1; o < 16; o <<= 1) h += __shfl_xor(h, o, 16);
      if (j == 0){ neS[0][i] = h; out_ne[blk*16+i] += h; }
    }
  }
  __syncthreads();
  if (tid == 0){
    float s = 0.f;
    #pragma unroll
    for (int i = 0; i < 16; i++) s += neS[0][i];
    atomicAdd(&out_ctr[(blk>>4)*3 + 1 + t], s);
  }
}

// ---------------------------------------------------------------- Coulomb + dipole: 4 j-chunks/graph,
// broadcast LDS reads (uniform j across block -> zero bank conflicts), row = tid.
__global__ __launch_bounds__(256) void k_coul(
    const float* __restrict__ q, const float* __restrict__ pos,
    const float* __restrict__ ctr, float* __restrict__ te, float* __restrict__ dip)
{
  __shared__ float qs[256], px[256], py[256], pz[256];
  __shared__ float red[4], redd[12];
  int g = blockIdx.x >> 2, ch = blockIdx.x & 3;
  int tid = threadIdx.x;
  int base = g*256;
  qs[tid] = q[base+tid];
  px[tid] = pos[(base+tid)*3];
  py[tid] = pos[(base+tid)*3+1];
  pz[tid] = pos[(base+tid)*3+2];
  __syncthreads();
  float qi = qs[tid], xi = px[tid], yi = py[tid], zi = pz[tid];
  float srow = 0.f;
  int j0 = ch*64;
  #pragma unroll 4
  for (int u = 0; u < 64; u++){
    int j = j0 + u;                      // block-uniform -> LDS broadcast
    float dx = xi-px[j], dy = yi-py[j], dz = zi-pz[j];
    float r = sqrtf(dx*dx+dy*dy+dz*dz + 1e-12f);
    float v = erff(0.5f*r)/r;
    srow += (j == tid) ? 0.f : qs[j]*v;
  }
  int wv = tid>>6, ln = tid&63;
  float ev = 0.5f*qi*srow;
  #pragma unroll
  for (int o = 32; o > 0; o >>= 1) ev += __shfl_down(ev, o, 64);
  if (ln == 0) red[wv] = ev;
  if (ch == 0){
    float vx = qi*xi, vy = qi*yi, vz = qi*zi;
    #pragma unroll
    for (int o = 32; o > 0; o >>= 1){
      vx += __shfl_down(vx, o, 64);
      vy += __shfl_down(vy, o, 64);
      vz += __shfl_down(vz, o, 64);
    }
    if (ln == 0){ redd[wv*3] = vx; redd[wv*3+1] = vy; redd[wv*3+2] = vz; }
  }
  __syncthreads();
  if (tid == 0){
    float e = red[0]+red[1]+red[2]+red[3];
    if (ch == 0) e += ctr[g*3] + ctr[g*3+1] + ctr[g*3+2];
    atomicAdd(&te[g], e);
  }
  if (ch == 0 && tid < 3)
    dip[g*3+tid] = redd[tid] + redd[3+tid] + redd[6+tid] + redd[9+tid];
}

// ---------------------------------------------------------------- launch
extern "C" void kernel_launch(void* const* d_in, const int* in_sizes, int n_in,
                              void* d_out, int out_size, void* d_ws, size_t ws_size,
                              hipStream_t stream)
{
  (void)in_sizes; (void)n_in; (void)out_size; (void)ws_size;
  const float* attrs   = (const float*)d_in[0];
  const float* pos     = (const float*)d_in[1];
  const int*   ei      = (const int*)d_in[2];
  const float* W_embed = (const float*)d_in[4];
  const float* E0      = (const float*)d_in[5];
  const float* rW1     = (const float*)d_in[6];
  const float* rW2     = (const float*)d_in[7];
  const float* rW3     = (const float*)d_in[8];
  const float* rW4     = (const float*)d_in[9];
  const float* Wmix    = (const float*)d_in[10];
  const float* Wsc     = (const float*)d_in[11];
  const float* w2      = (const float*)d_in[12];
  const float* w3      = (const float*)d_in[13];
  const float* Wr0     = (const float*)d_in[14];
  const float* Wh      = (const float*)d_in[15];
  const float* Wo      = (const float*)d_in[16];
  const float* Wq      = (const float*)d_in[17];

  char* base = (char*)d_ws;
  _Float16* efH   = (_Float16*)base; base += (size_t)NEDGE*32*2;
  _Float16* shH   = (_Float16*)base; base += (size_t)NEDGE*16*2 + 8192;  // slack for chunk-aligned staging reads
  _Float16* RCh   = (_Float16*)base; base += (size_t)NEDGE*64*2 + 32768; // slack for stage over-read
  _Float16* sH    = (_Float16*)base; base += (size_t)NNODE*64*2;
  _Float16* feats1= (_Float16*)base; base += (size_t)9*NNODE*64*2;
  _Float16* wH    = (_Float16*)base; base += (size_t)2*28*512*2;
  _Float16* wmixH = (_Float16*)base; base += (size_t)2*24*512*2;
  int*      deg   = (int*)base;      base += (size_t)NNODE*4;
  int*      offs  = (int*)base;      base += (size_t)(NNODE+1)*4;
  int*      cursor= (int*)base;      base += (size_t)NNODE*4;
  int*      srcC  = (int*)base;      base += (size_t)NEDGE*4;
  int*      zidx  = (int*)base;      base += (size_t)NNODE*4;

  float* out_te  = (float*)d_out;
  float* out_ne  = out_te  + NGRAPH;
  float* out_ctr = out_ne  + NNODE;
  float* out_q   = out_ctr + NGRAPH*3;
  float* out_dip = out_q   + NNODE;

  k_init0<<<4162, 256, 0, stream>>>(attrs, E0, W_embed, rW1, rW2, rW3, rW4, Wmix,
      zidx, sH, wH, wmixH, deg, cursor, out_ne, out_ctr, out_q, out_te, out_dip);
  k_count<<<NEDGE/256, 256, 0, stream>>>(ei, pos, deg);
  k_scan <<<1, 1024, 0, stream>>>(deg, offs);
  k_fill <<<NEDGE/256, 256, 0, stream>>>(ei, pos, offs, cursor, srcC, efH, shH);

  for (int t = 0; t < 2; t++){
    const _Float16* sprev = t ? feats1 : sH;   // plane 0 of feats1 == next-iter node scalars
    k_R <<<NEDGE/64, 256, 0, stream>>>(efH, srcC, sprev, offs+NNODE,
        wH + (size_t)t*28*512, RCh);
    k_am<<<NNODE/16, 256, 0, stream>>>(RCh, shH, offs, sH, feats1,
        wmixH + (size_t)t*24*512, zidx,
        Wsc + t*NELEM*CDIM, w2 + t*NELEM*CDIM, w3 + t*NELEM*CDIM, Wq + t*CDIM,
        Wr0, Wh, Wo, out_ne, out_ctr, out_q, t);
  }
  k_coul<<<NGRAPH*4, 256, 0, stream>>>(out_q, pos, out_ctr, out_te, out_dip);
}